// Round 1
// baseline (3626.910 us; speedup 1.0000x reference)
//
#include <hip/hip_runtime.h>
#include <stdint.h>

namespace {

constexpr int B_ROWS = 131072;

typedef __attribute__((ext_vector_type(8))) short bf16x8;
typedef __attribute__((ext_vector_type(4))) float f32x4;

__device__ __forceinline__ unsigned short f2bf(float f) {
  unsigned u = __builtin_bit_cast(unsigned, f);
  u += 0x7fffu + ((u >> 16) & 1u);
  return (unsigned short)(u >> 16);
}
__device__ __forceinline__ float bf2f(unsigned short h) {
  unsigned u = ((unsigned)h) << 16;
  return __builtin_bit_cast(float, u);
}
__device__ __forceinline__ float sigm(float v) { return 1.0f / (1.0f + __expf(-v)); }

// ---------- weight packing (runs every call; ~14M elems, cheap) ----------

// Wt[n][k] = W[k][n], 512x512 fp32 -> bf16 transposed
__global__ void pack_t_k(const float* __restrict__ W, unsigned short* __restrict__ Wt) {
  int idx = blockIdx.x * 256 + threadIdx.x;  // 512*512
  int n = idx >> 9, k = idx & 511;
  Wt[idx] = f2bf(W[(k << 9) + n]);
}

// Wt_zgr[l][n][k], n in [0,1536): Z|G|R blocks; k<512 = x-part (sum of two W), else S-part.
__global__ void pack_zgr_k(const float* __restrict__ dgmW, unsigned short* __restrict__ Wt) {
  long idx = (long)blockIdx.x * 256 + threadIdx.x;  // 3*1536*1024
  int l = (int)(idx / (1536 * 1024));
  int rest = (int)(idx - (long)l * (1536 * 1024));
  int n = rest >> 10, k = rest & 1023;
  int g = n >> 9, nn = n & 511;
  const int xi0[3] = {0, 3, 6};
  const int xi1[3] = {2, 4, 8};
  const int si[3] = {1, 5, 7};
  float v;
  if (k < 512)
    v = dgmW[(((long)(l * 12 + xi0[g]) << 9) + k) * 512 + nn] +
        dgmW[(((long)(l * 12 + xi1[g]) << 9) + k) * 512 + nn];
  else
    v = dgmW[(((long)(l * 12 + si[g]) << 9) + (k - 512)) * 512 + nn];
  Wt[idx] = f2bf(v);
}

// Wt_h[l][n][k]: k<512 -> W9+W11 (x-part), else W10 (SR-part)
__global__ void pack_h_k(const float* __restrict__ dgmW, unsigned short* __restrict__ Wt) {
  long idx = (long)blockIdx.x * 256 + threadIdx.x;  // 3*512*1024
  int l = (int)(idx / (512 * 1024));
  int rest = (int)(idx - (long)l * (512 * 1024));
  int n = rest >> 10, k = rest & 1023;
  float v;
  if (k < 512)
    v = dgmW[(((long)(l * 12 + 9) << 9) + k) * 512 + n] +
        dgmW[(((long)(l * 12 + 11) << 9) + k) * 512 + n];
  else
    v = dgmW[(((long)(l * 12 + 10) << 9) + (k - 512)) * 512 + n];
  Wt[idx] = f2bf(v);
}

__global__ void pack_bias_k(const float* __restrict__ dgmb, float* __restrict__ bzgr,
                            float* __restrict__ bh) {
  int idx = blockIdx.x * 256 + threadIdx.x;  // 3*2048
  if (idx >= 3 * 2048) return;
  int l = idx >> 11, n = idx & 2047;
  const float* bl = dgmb + l * 12 * 512;
  if (n < 1536) {
    int g = n >> 9, nn = n & 511;
    bzgr[l * 1536 + n] =
        bl[(g * 3 + 0) * 512 + nn] + bl[(g * 3 + 1) * 512 + nn] + bl[(g * 3 + 2) * 512 + nn];
  } else {
    int nn = n - 1536;
    bh[l * 512 + nn] = bl[9 * 512 + nn] + bl[10 * 512 + nn] + bl[11 * 512 + nn];
  }
}

// ---------- front input layer: x0 = tanh([X,t] @ W_in + b_in), K=3 ----------
__global__ void front0_k(const float* __restrict__ X, const float* __restrict__ t,
                         const float* __restrict__ Win, const float* __restrict__ bin,
                         unsigned short* __restrict__ x0, long row0) {
  long idx = (long)blockIdx.x * 256 + threadIdx.x;  // rows*512
  long r = idx >> 9;
  int c = (int)(idx & 511);
  long gr = row0 + r;
  float a = X[gr * 2] * Win[c] + X[gr * 2 + 1] * Win[512 + c] + t[gr] * Win[1024 + c] + bin[c];
  x0[idx] = f2bf(tanhf(a));
}

// ---------- output head: out = S @ W_out + b_out ----------
__global__ void head_k(const unsigned short* __restrict__ S, const float* __restrict__ Wout,
                       const float* __restrict__ bout, float* __restrict__ out, long row0) {
  const int lane = threadIdx.x & 63, wid = threadIdx.x >> 6;
  const long r = (long)blockIdx.x * 4 + wid;
  bf16x8 sv = *(const bf16x8*)&S[r * 512 + lane * 8];
  float sum = 0.f;
#pragma unroll
  for (int i = 0; i < 8; ++i) sum += bf2f((unsigned short)sv[i]) * Wout[lane * 8 + i];
#pragma unroll
  for (int off = 32; off > 0; off >>= 1) sum += __shfl_down(sum, off);
  if (lane == 0) out[row0 + r] = sum + bout[0];
}

// ---------- core GEMM: C[row][col] = act( sum_k A[row][k]*Wt[col][k] + bias[col] ) ----------
// A gathered from a0 (k<512) / a1 (k>=512), both [rows][512] bf16 row-major.
// Wt [N][K] bf16 row-major (pre-transposed). 128x128 tile, BK=64, 4 waves (2x2 of 64x64).
// EPI: 0 = tanh->o0 ; 1 = copy->o0,o1 ; 2 = gates (Z*S->o0, 1-G->o1, S*R->o2, reads S=e0)
//      3 = S update: o0 = e0*tanh(v) + e1   (e0=1-G, e1=Z*S)
template <int EPI, int KTILES>
__global__ __launch_bounds__(256, 2) void gemm_k(
    const unsigned short* __restrict__ a0, const unsigned short* __restrict__ a1,
    const unsigned short* __restrict__ wt, const float* __restrict__ bias,
    unsigned short* __restrict__ o0, unsigned short* __restrict__ o1,
    unsigned short* __restrict__ o2, const unsigned short* __restrict__ e0,
    const unsigned short* __restrict__ e1) {
  constexpr int K = KTILES * 64;
  __shared__ __align__(16) unsigned short As[128 * 64];
  __shared__ __align__(16) unsigned short Bs[128 * 64];
  const int tid = threadIdx.x;
  const int lane = tid & 63;
  const int wid = tid >> 6;
  const int wm = wid >> 1, wn = wid & 1;
  const long brow = (long)blockIdx.y * 128;
  const int bcol = blockIdx.x * 128;
  f32x4 acc[4][4] = {};

  for (int kt = 0; kt < KTILES; ++kt) {
    const unsigned short* asrc = (kt < 8) ? a0 : a1;
    const int kloc = (kt & 7) * 64;
    __syncthreads();
#pragma unroll
    for (int i = 0; i < 4; ++i) {
      const int c = tid + 256 * i;  // chunk of 8 bf16 (16B)
      const int r = c >> 3, k8 = (c & 7) * 8;
      __builtin_amdgcn_global_load_lds(
          (const __attribute__((address_space(1))) void*)(asrc + (brow + r) * 512 + kloc + k8),
          (__attribute__((address_space(3))) void*)(&As[c * 8]), 16, 0, 0);
      __builtin_amdgcn_global_load_lds(
          (const __attribute__((address_space(1))) void*)(wt + (long)(bcol + r) * K + kt * 64 + k8),
          (__attribute__((address_space(3))) void*)(&Bs[c * 8]), 16, 0, 0);
    }
    __syncthreads();
#pragma unroll
    for (int ks = 0; ks < 2; ++ks) {
      bf16x8 af[4], bfv[4];
#pragma unroll
      for (int m = 0; m < 4; ++m)
        af[m] = *(const bf16x8*)&As[(wm * 64 + m * 16 + (lane & 15)) * 64 + ks * 32 + (lane >> 4) * 8];
#pragma unroll
      for (int n = 0; n < 4; ++n)
        bfv[n] = *(const bf16x8*)&Bs[(wn * 64 + n * 16 + (lane & 15)) * 64 + ks * 32 + (lane >> 4) * 8];
#pragma unroll
      for (int m = 0; m < 4; ++m)
#pragma unroll
        for (int n = 0; n < 4; ++n)
          acc[m][n] = __builtin_amdgcn_mfma_f32_16x16x32_bf16(af[m], bfv[n], acc[m][n], 0, 0, 0);
    }
  }

  const int g = bcol >> 9;  // gate group (uniform per block)
#pragma unroll
  for (int m = 0; m < 4; ++m) {
#pragma unroll
    for (int n = 0; n < 4; ++n) {
      const int col = bcol + wn * 64 + n * 16 + (lane & 15);
      const float bs = bias[col];
#pragma unroll
      for (int j = 0; j < 4; ++j) {
        const long row = brow + wm * 64 + m * 16 + (lane >> 4) * 4 + j;
        float v = acc[m][n][j] + bs;
        if constexpr (EPI == 0) {
          o0[row * 512 + col] = f2bf(tanhf(v));
        } else if constexpr (EPI == 1) {
          unsigned short b = f2bf(v);
          o0[row * 512 + col] = b;
          o1[row * 512 + col] = b;
        } else if constexpr (EPI == 2) {
          const int nn = col & 511;
          const float sgv = sigm(v);
          if (g == 0) {
            o0[row * 512 + nn] = f2bf(sgv * bf2f(e0[row * 512 + nn]));  // Z*S
          } else if (g == 1) {
            o1[row * 512 + nn] = f2bf(1.0f - sgv);  // 1-G
          } else {
            o2[row * 512 + nn] = f2bf(sgv * bf2f(e0[row * 512 + nn]));  // S*R
          }
        } else {
          const float h = tanhf(v);
          const float omg = bf2f(e0[row * 512 + col]);
          const float zs = bf2f(e1[row * 512 + col]);
          o0[row * 512 + col] = f2bf(omg * h + zs);  // S_new
        }
      }
    }
  }
}

}  // namespace

extern "C" void kernel_launch(void* const* d_in, const int* in_sizes, int n_in,
                              void* d_out, int out_size, void* d_ws, size_t ws_size,
                              hipStream_t stream) {
  const float* X = (const float*)d_in[0];
  const float* t = (const float*)d_in[1];
  const float* W_in = (const float*)d_in[2];
  const float* b_in = (const float*)d_in[3];
  const float* W_h1 = (const float*)d_in[4];
  const float* b_h1 = (const float*)d_in[5];
  const float* W_hd = (const float*)d_in[6];
  const float* b_hd = (const float*)d_in[7];
  const float* dgm_W = (const float*)d_in[8];
  const float* dgm_b = (const float*)d_in[9];
  const float* W_out = (const float*)d_in[10];
  const float* b_out = (const float*)d_in[11];
  float* out = (float*)d_out;
  char* ws = (char*)d_ws;

  size_t off = 0;
  auto alloc = [&](size_t bytes) {
    size_t o = off;
    off = (off + bytes + 255) & ~(size_t)255;
    return o;
  };
  size_t o_wth1 = alloc((size_t)512 * 512 * 2);
  size_t o_wthd = alloc((size_t)512 * 512 * 2);
  size_t o_wtzgr = alloc((size_t)3 * 1536 * 1024 * 2);
  size_t o_wth = alloc((size_t)3 * 512 * 1024 * 2);
  size_t o_bzgr = alloc((size_t)3 * 1536 * 4);
  size_t o_bh = alloc((size_t)3 * 512 * 4);
  size_t actoff = off;

  unsigned short* wth1 = (unsigned short*)(ws + o_wth1);
  unsigned short* wthd = (unsigned short*)(ws + o_wthd);
  unsigned short* wtzgr = (unsigned short*)(ws + o_wtzgr);
  unsigned short* wth = (unsigned short*)(ws + o_wth);
  float* bzgr = (float*)(ws + o_bzgr);
  float* bh = (float*)(ws + o_bh);

  // chunk batch so 5 bf16 [R,512] activation buffers fit in remaining ws
  size_t avail = ws_size > actoff ? ws_size - actoff : 0;
  int nch = 1;
  while (nch < 1024 && (size_t)(B_ROWS / nch) * 512 * 2 * 5 > avail) nch <<= 1;
  const int R = B_ROWS / nch;
  unsigned short* xb = (unsigned short*)(ws + actoff);
  unsigned short* Sb = xb + (size_t)R * 512;
  unsigned short* ZSb = Sb + (size_t)R * 512;
  unsigned short* OGb = ZSb + (size_t)R * 512;
  unsigned short* SRb = OGb + (size_t)R * 512;

  pack_t_k<<<1024, 256, 0, stream>>>(W_h1, wth1);
  pack_t_k<<<1024, 256, 0, stream>>>(W_hd, wthd);
  pack_zgr_k<<<18432, 256, 0, stream>>>(dgm_W, wtzgr);
  pack_h_k<<<6144, 256, 0, stream>>>(dgm_W, wth);
  pack_bias_k<<<24, 256, 0, stream>>>(dgm_b, bzgr, bh);

  for (int c = 0; c < nch; ++c) {
    long row0 = (long)c * R;
    dim3 g4(4, R / 128), g12(12, R / 128);
    // x0 = tanh(inp@W_in + b_in)  -> ZSb (scratch)
    front0_k<<<R * 2, 256, 0, stream>>>(X, t, W_in, b_in, ZSb, row0);
    // x1 = tanh(x0@W_h1 + b_h1)   -> OGb (scratch)
    gemm_k<0, 8><<<g4, 256, 0, stream>>>(ZSb, nullptr, wth1, b_h1, OGb, nullptr, nullptr,
                                         nullptr, nullptr);
    // x = x1@W_hd + b_hd          -> xb and Sb
    gemm_k<1, 8><<<g4, 256, 0, stream>>>(OGb, nullptr, wthd, b_hd, xb, Sb, nullptr,
                                         nullptr, nullptr);
    for (int l = 0; l < 3; ++l) {
      // gates: [x|S] @ Wzgr -> ZS, 1-G, SR
      gemm_k<2, 16><<<g12, 256, 0, stream>>>(xb, Sb, wtzgr + (size_t)l * 1536 * 1024,
                                             bzgr + l * 1536, ZSb, OGb, SRb, Sb, nullptr);
      // H + S update: [x|SR] @ Wh ; S = (1-G)*tanh + Z*S
      gemm_k<3, 16><<<g4, 256, 0, stream>>>(xb, SRb, wth + (size_t)l * 512 * 1024,
                                            bh + l * 512, Sb, nullptr, nullptr, OGb, ZSb);
    }
    head_k<<<R / 4, 256, 0, stream>>>(Sb, W_out, b_out, out, row0);
  }
}

// Round 2
// 3375.812 us; speedup vs baseline: 1.0744x; 1.0744x over previous
//
#include <hip/hip_runtime.h>
#include <stdint.h>

namespace {

constexpr int B_ROWS = 131072;

typedef __attribute__((ext_vector_type(8))) short bf16x8;
typedef __attribute__((ext_vector_type(4))) float f32x4;

__device__ __forceinline__ unsigned short f2bf(float f) {
  unsigned u = __builtin_bit_cast(unsigned, f);
  u += 0x7fffu + ((u >> 16) & 1u);
  return (unsigned short)(u >> 16);
}
__device__ __forceinline__ float bf2f(unsigned short h) {
  unsigned u = ((unsigned)h) << 16;
  return __builtin_bit_cast(float, u);
}
__device__ __forceinline__ float sigm(float v) { return 1.0f / (1.0f + __expf(-v)); }

// ---------- weight packing ----------

__global__ void pack_t_k(const float* __restrict__ W, unsigned short* __restrict__ Wt) {
  int idx = blockIdx.x * 256 + threadIdx.x;  // 512*512
  int n = idx >> 9, k = idx & 511;
  Wt[idx] = f2bf(W[(k << 9) + n]);
}

__global__ void pack_zgr_k(const float* __restrict__ dgmW, unsigned short* __restrict__ Wt) {
  long idx = (long)blockIdx.x * 256 + threadIdx.x;  // 3*1536*1024
  int l = (int)(idx / (1536 * 1024));
  int rest = (int)(idx - (long)l * (1536 * 1024));
  int n = rest >> 10, k = rest & 1023;
  int g = n >> 9, nn = n & 511;
  const int xi0[3] = {0, 3, 6};
  const int xi1[3] = {2, 4, 8};
  const int si[3] = {1, 5, 7};
  float v;
  if (k < 512)
    v = dgmW[(((long)(l * 12 + xi0[g]) << 9) + k) * 512 + nn] +
        dgmW[(((long)(l * 12 + xi1[g]) << 9) + k) * 512 + nn];
  else
    v = dgmW[(((long)(l * 12 + si[g]) << 9) + (k - 512)) * 512 + nn];
  Wt[idx] = f2bf(v);
}

__global__ void pack_h_k(const float* __restrict__ dgmW, unsigned short* __restrict__ Wt) {
  long idx = (long)blockIdx.x * 256 + threadIdx.x;  // 3*512*1024
  int l = (int)(idx / (512 * 1024));
  int rest = (int)(idx - (long)l * (512 * 1024));
  int n = rest >> 10, k = rest & 1023;
  float v;
  if (k < 512)
    v = dgmW[(((long)(l * 12 + 9) << 9) + k) * 512 + n] +
        dgmW[(((long)(l * 12 + 11) << 9) + k) * 512 + n];
  else
    v = dgmW[(((long)(l * 12 + 10) << 9) + (k - 512)) * 512 + n];
  Wt[idx] = f2bf(v);
}

__global__ void pack_bias_k(const float* __restrict__ dgmb, float* __restrict__ bzgr,
                            float* __restrict__ bh) {
  int idx = blockIdx.x * 256 + threadIdx.x;  // 3*2048
  if (idx >= 3 * 2048) return;
  int l = idx >> 11, n = idx & 2047;
  const float* bl = dgmb + l * 12 * 512;
  if (n < 1536) {
    int g = n >> 9, nn = n & 511;
    bzgr[l * 1536 + n] =
        bl[(g * 3 + 0) * 512 + nn] + bl[(g * 3 + 1) * 512 + nn] + bl[(g * 3 + 2) * 512 + nn];
  } else {
    int nn = n - 1536;
    bh[l * 512 + nn] = bl[9 * 512 + nn] + bl[10 * 512 + nn] + bl[11 * 512 + nn];
  }
}

// ---------- front input layer ----------
__global__ void front0_k(const float* __restrict__ X, const float* __restrict__ t,
                         const float* __restrict__ Win, const float* __restrict__ bin,
                         unsigned short* __restrict__ x0, long row0) {
  long idx = (long)blockIdx.x * 256 + threadIdx.x;  // rows*512
  long r = idx >> 9;
  int c = (int)(idx & 511);
  long gr = row0 + r;
  float a = X[gr * 2] * Win[c] + X[gr * 2 + 1] * Win[512 + c] + t[gr] * Win[1024 + c] + bin[c];
  x0[idx] = f2bf(tanhf(a));
}

// ---------- output head ----------
__global__ void head_k(const unsigned short* __restrict__ S, const float* __restrict__ Wout,
                       const float* __restrict__ bout, float* __restrict__ out, long row0) {
  const int lane = threadIdx.x & 63, wid = threadIdx.x >> 6;
  const long r = (long)blockIdx.x * 4 + wid;
  bf16x8 sv = *(const bf16x8*)&S[r * 512 + lane * 8];
  float sum = 0.f;
#pragma unroll
  for (int i = 0; i < 8; ++i) sum += bf2f((unsigned short)sv[i]) * Wout[lane * 8 + i];
#pragma unroll
  for (int off = 32; off > 0; off >>= 1) sum += __shfl_down(sum, off);
  if (lane == 0) out[row0 + r] = sum + bout[0];
}

// ---------- 256x256 8-phase GEMM (T1+T2+T3+T4+T5) ----------
// C[row][col] = act( sum_k A[row][k]*Wt[col][k] + bias[col] )
// A from a0 (k<512) / a1 (k>=512), [rows][512] bf16. Wt [N][K] bf16.
// 512 thr = 8 waves (2M x 4N); per-wave out 128x64 = acc[8][4].
// LDS [2 buf][2 mat][2 ks][256][32] bf16 = 128 KiB, dynamic.
// Stage unit = (mat, ks) 16KB = 2 global_load_lds/thread. Swizzle:
// phys granule = logical granule ^ ((row>>1)&3), applied on BOTH the
// global source address and the ds_read address (LDS dest linear).
template <int EPI, int KTILES>
__global__ __launch_bounds__(512, 2) void gemm8_k(
    const unsigned short* __restrict__ a0, const unsigned short* __restrict__ a1,
    const unsigned short* __restrict__ wt, const float* __restrict__ bias,
    unsigned short* __restrict__ o0, unsigned short* __restrict__ o1,
    unsigned short* __restrict__ o2, const unsigned short* __restrict__ e0,
    const unsigned short* __restrict__ e1) {
  constexpr int K = KTILES * 64;
  constexpr int NT = KTILES;
  extern __shared__ unsigned short lds[];
  const int tid = threadIdx.x;
  const int lane = tid & 63;
  const int wid = tid >> 6;
  const int wm = wid >> 2, wn = wid & 3;

  // T1: bijective XCD swizzle (m204); col-block fastest -> 6 consecutive
  // blocks share one A-panel inside one XCD's L2.
  const int gx = gridDim.x;
  const int nwg = gx * (int)gridDim.y;
  const int orig = (int)blockIdx.y * gx + (int)blockIdx.x;
  const int q = nwg >> 3, rr = nwg & 7;
  const int xcd = orig & 7, lo = orig >> 3;
  const int wg = ((xcd < rr) ? xcd * (q + 1) : rr * (q + 1) + (xcd - rr) * q) + lo;
  const long brow = (long)(wg / gx) * 256;
  const int bcol = (wg % gx) * 256;

  f32x4 acc[8][4] = {};
  bf16x8 af[4], bf[4];

#define STAGE_A(db, kt, ks_)                                                                   \
  do {                                                                                         \
    const unsigned short* _src = ((kt) < 8) ? a0 : a1;                                         \
    const int _koff = (((kt)&7) << 6) + (ks_)*32;                                              \
    _Pragma("unroll") for (int _i = 0; _i < 2; ++_i) {                                         \
      const int _c = tid + (_i << 9);                                                          \
      const int _r = _c >> 2;                                                                  \
      const int _gl = (_c & 3) ^ ((_r >> 1) & 3);                                              \
      __builtin_amdgcn_global_load_lds(                                                        \
          (const __attribute__((address_space(1))) void*)(_src + (brow + _r) * 512 + _koff +   \
                                                          _gl * 8),                            \
          (__attribute__((address_space(3))) void*)(lds + (db)*32768 + (ks_)*8192 + _c * 8),   \
          16, 0, 0);                                                                           \
    }                                                                                          \
  } while (0)

#define STAGE_B(db, kt, ks_)                                                                   \
  do {                                                                                         \
    _Pragma("unroll") for (int _i = 0; _i < 2; ++_i) {                                         \
      const int _c = tid + (_i << 9);                                                          \
      const int _r = _c >> 2;                                                                  \
      const int _gl = (_c & 3) ^ ((_r >> 1) & 3);                                              \
      __builtin_amdgcn_global_load_lds(                                                        \
          (const __attribute__((address_space(1))) void*)(wt + (size_t)(bcol + _r) * K +       \
                                                          ((kt) << 6) + (ks_)*32 + _gl * 8),   \
          (__attribute__((address_space(3))) void*)(lds + (db)*32768 + 16384 + (ks_)*8192 +    \
                                                    _c * 8),                                   \
          16, 0, 0);                                                                           \
    }                                                                                          \
  } while (0)

#define LOAD_A(mh, ks_)                                                                        \
  do {                                                                                         \
    _Pragma("unroll") for (int _m = 0; _m < 4; ++_m) {                                         \
      const int _row = wm * 128 + ((mh)*4 + _m) * 16 + (lane & 15);                            \
      const int _gp = (lane >> 4) ^ ((_row >> 1) & 3);                                         \
      af[_m] = *(const bf16x8*)(lds + cb * 32768 + (ks_)*8192 + _row * 32 + _gp * 8);          \
    }                                                                                          \
  } while (0)

#define LOAD_B(ks_)                                                                            \
  do {                                                                                         \
    _Pragma("unroll") for (int _n = 0; _n < 4; ++_n) {                                         \
      const int _row = wn * 64 + _n * 16 + (lane & 15);                                        \
      const int _gp = (lane >> 4) ^ ((_row >> 1) & 3);                                         \
      bf[_n] = *(const bf16x8*)(lds + cb * 32768 + 16384 + (ks_)*8192 + _row * 32 + _gp * 8);  \
    }                                                                                          \
  } while (0)

#define BAR_IN()                                          \
  do {                                                    \
    __builtin_amdgcn_s_barrier();                         \
    asm volatile("s_waitcnt lgkmcnt(0)" ::: "memory");    \
    __builtin_amdgcn_sched_barrier(0);                    \
  } while (0)

#define MFMA_Q(mh)                                                                             \
  do {                                                                                         \
    __builtin_amdgcn_s_setprio(1);                                                             \
    _Pragma("unroll") for (int _m = 0; _m < 4; ++_m) _Pragma("unroll") for (int _n = 0;        \
                                                                            _n < 4; ++_n)      \
        acc[(mh)*4 + _m][_n] = __builtin_amdgcn_mfma_f32_16x16x32_bf16(                        \
            af[_m], bf[_n], acc[(mh)*4 + _m][_n], 0, 0, 0);                                    \
    __builtin_amdgcn_s_setprio(0);                                                             \
  } while (0)

  // prologue: tile0 complete (8 loads) + 3 units of tile1 (6 loads)
  STAGE_A(0, 0, 0);
  STAGE_B(0, 0, 0);
  STAGE_A(0, 0, 1);
  STAGE_B(0, 0, 1);
  STAGE_B(1, 1, 0);
  STAGE_A(1, 1, 0);
  STAGE_B(1, 1, 1);
  asm volatile("s_waitcnt vmcnt(6)" ::: "memory");
  __builtin_amdgcn_s_barrier();

  for (int t = 0; t < NT; ++t) {
    const int cb = t & 1;
    // phase 1: quadrant (m0-3, ks0); stage (t+1).Aks1 -> other buf
    LOAD_B(0);
    LOAD_A(0, 0);
    if (t + 1 < NT) STAGE_A(cb ^ 1, t + 1, 1);
    BAR_IN();
    MFMA_Q(0);
    __builtin_amdgcn_s_barrier();
    // phase 2: (m4-7, ks0), B reused; stage (t+2).Bks0 (B-ks0 last read ph1)
    LOAD_A(1, 0);
    if (t + 2 < NT) STAGE_B(cb, t + 2, 0);
    BAR_IN();
    MFMA_Q(1);
    __builtin_amdgcn_s_barrier();
    // phase 3: (m0-3, ks1); stage (t+2).Aks0 (A-ks0 last read ph2)
    LOAD_B(1);
    LOAD_A(0, 1);
    if (t + 2 < NT) STAGE_A(cb, t + 2, 0);
    BAR_IN();
    MFMA_Q(0);
    __builtin_amdgcn_s_barrier();
    // phase 4: (m4-7, ks1); stage (t+2).Bks1 (B-ks1 last read ph3)
    LOAD_A(1, 1);
    if (t + 2 < NT) STAGE_B(cb, t + 2, 1);
    BAR_IN();
    MFMA_Q(1);
    if (t >= NT - 2)
      asm volatile("s_waitcnt vmcnt(0)" ::: "memory");
    else
      asm volatile("s_waitcnt vmcnt(6)" ::: "memory");
    __builtin_amdgcn_s_barrier();
  }

#undef STAGE_A
#undef STAGE_B
#undef LOAD_A
#undef LOAD_B
#undef BAR_IN
#undef MFMA_Q

  // epilogue
#pragma unroll
  for (int m = 0; m < 8; ++m) {
#pragma unroll
    for (int n = 0; n < 4; ++n) {
      const int col = bcol + wn * 64 + n * 16 + (lane & 15);
      const float bs = bias[col];
#pragma unroll
      for (int j = 0; j < 4; ++j) {
        const long row = brow + wm * 128 + m * 16 + (lane >> 4) * 4 + j;
        float v = acc[m][n][j] + bs;
        if constexpr (EPI == 0) {
          o0[row * 512 + col] = f2bf(tanhf(v));
        } else if constexpr (EPI == 1) {
          unsigned short b = f2bf(v);
          o0[row * 512 + col] = b;
          o1[row * 512 + col] = b;
        } else if constexpr (EPI == 2) {
          const int g = col >> 9;
          const int nn = col & 511;
          const float sgv = sigm(v);
          if (g == 0) {
            o0[row * 512 + nn] = f2bf(sgv * bf2f(e0[row * 512 + nn]));  // Z*S
          } else if (g == 1) {
            o1[row * 512 + nn] = f2bf(1.0f - sgv);  // 1-G
          } else {
            o2[row * 512 + nn] = f2bf(sgv * bf2f(e0[row * 512 + nn]));  // S*R
          }
        } else {
          const float h = tanhf(v);
          const float omg = bf2f(e0[row * 512 + col]);
          const float zs = bf2f(e1[row * 512 + col]);
          o0[row * 512 + col] = f2bf(omg * h + zs);  // S_new
        }
      }
    }
  }
}

}  // namespace

extern "C" void kernel_launch(void* const* d_in, const int* in_sizes, int n_in,
                              void* d_out, int out_size, void* d_ws, size_t ws_size,
                              hipStream_t stream) {
  const float* X = (const float*)d_in[0];
  const float* t = (const float*)d_in[1];
  const float* W_in = (const float*)d_in[2];
  const float* b_in = (const float*)d_in[3];
  const float* W_h1 = (const float*)d_in[4];
  const float* b_h1 = (const float*)d_in[5];
  const float* W_hd = (const float*)d_in[6];
  const float* b_hd = (const float*)d_in[7];
  const float* dgm_W = (const float*)d_in[8];
  const float* dgm_b = (const float*)d_in[9];
  const float* W_out = (const float*)d_in[10];
  const float* b_out = (const float*)d_in[11];
  float* out = (float*)d_out;
  char* ws = (char*)d_ws;

  // allow 128 KiB dynamic LDS for the GEMM kernels (host-side, capture-safe)
  (void)hipFuncSetAttribute((const void*)&gemm8_k<0, 8>,
                            hipFuncAttributeMaxDynamicSharedMemorySize, 131072);
  (void)hipFuncSetAttribute((const void*)&gemm8_k<1, 8>,
                            hipFuncAttributeMaxDynamicSharedMemorySize, 131072);
  (void)hipFuncSetAttribute((const void*)&gemm8_k<2, 16>,
                            hipFuncAttributeMaxDynamicSharedMemorySize, 131072);
  (void)hipFuncSetAttribute((const void*)&gemm8_k<3, 16>,
                            hipFuncAttributeMaxDynamicSharedMemorySize, 131072);

  size_t off = 0;
  auto alloc = [&](size_t bytes) {
    size_t o = off;
    off = (off + bytes + 255) & ~(size_t)255;
    return o;
  };
  size_t o_wth1 = alloc((size_t)512 * 512 * 2);
  size_t o_wthd = alloc((size_t)512 * 512 * 2);
  size_t o_wtzgr = alloc((size_t)3 * 1536 * 1024 * 2);
  size_t o_wth = alloc((size_t)3 * 512 * 1024 * 2);
  size_t o_bzgr = alloc((size_t)3 * 1536 * 4);
  size_t o_bh = alloc((size_t)3 * 512 * 4);
  size_t actoff = off;

  unsigned short* wth1 = (unsigned short*)(ws + o_wth1);
  unsigned short* wthd = (unsigned short*)(ws + o_wthd);
  unsigned short* wtzgr = (unsigned short*)(ws + o_wtzgr);
  unsigned short* wth = (unsigned short*)(ws + o_wth);
  float* bzgr = (float*)(ws + o_bzgr);
  float* bh = (float*)(ws + o_bh);

  // chunk batch so 5 bf16 [R,512] activation buffers fit in remaining ws;
  // R must stay a multiple of 256 (tile height)
  size_t avail = ws_size > actoff ? ws_size - actoff : 0;
  int nch = 1;
  while (nch < 512 && (size_t)(B_ROWS / nch) * 512 * 2 * 5 > avail) nch <<= 1;
  const int R = B_ROWS / nch;
  unsigned short* xb = (unsigned short*)(ws + actoff);
  unsigned short* Sb = xb + (size_t)R * 512;
  unsigned short* ZSb = Sb + (size_t)R * 512;
  unsigned short* OGb = ZSb + (size_t)R * 512;
  unsigned short* SRb = OGb + (size_t)R * 512;

  pack_t_k<<<1024, 256, 0, stream>>>(W_h1, wth1);
  pack_t_k<<<1024, 256, 0, stream>>>(W_hd, wthd);
  pack_zgr_k<<<18432, 256, 0, stream>>>(dgm_W, wtzgr);
  pack_h_k<<<6144, 256, 0, stream>>>(dgm_W, wth);
  pack_bias_k<<<24, 256, 0, stream>>>(dgm_b, bzgr, bh);

  for (int c = 0; c < nch; ++c) {
    long row0 = (long)c * R;
    dim3 g2(2, R / 256), g6(6, R / 256);
    // x0 = tanh(inp@W_in + b_in)  -> ZSb (scratch)
    front0_k<<<R * 2, 256, 0, stream>>>(X, t, W_in, b_in, ZSb, row0);
    // x1 = tanh(x0@W_h1 + b_h1)   -> OGb (scratch)
    gemm8_k<0, 8><<<g2, 512, 131072, stream>>>(ZSb, ZSb, wth1, b_h1, OGb, nullptr, nullptr,
                                               nullptr, nullptr);
    // x = x1@W_hd + b_hd          -> xb and Sb
    gemm8_k<1, 8><<<g2, 512, 131072, stream>>>(OGb, OGb, wthd, b_hd, xb, Sb, nullptr,
                                               nullptr, nullptr);
    for (int l = 0; l < 3; ++l) {
      // gates: [x|S] @ Wzgr -> Z*S, 1-G, S*R
      gemm8_k<2, 16><<<g6, 512, 131072, stream>>>(xb, Sb, wtzgr + (size_t)l * 1536 * 1024,
                                                  bzgr + l * 1536, ZSb, OGb, SRb, Sb, nullptr);
      // H + S update: [x|S*R] @ Wh ; S = (1-G)*tanh + Z*S
      gemm8_k<3, 16><<<g2, 512, 131072, stream>>>(xb, SRb, wth + (size_t)l * 512 * 1024,
                                                  bh + l * 512, Sb, nullptr, nullptr, OGb, ZSb);
    }
    head_k<<<R / 4, 256, 0, stream>>>(Sb, W_out, b_out, out, row0);
  }
}